// Round 9
// baseline (182.357 us; speedup 1.0000x reference)
//
#include <hip/hip_runtime.h>

typedef __attribute__((ext_vector_type(8)))  short bf16x8;   // MFMA A/B frag (4 VGPRs)
typedef __attribute__((ext_vector_type(4)))  float f32x4;    // 16x16 C/D frag
typedef __attribute__((ext_vector_type(16))) float f32x16;   // 32x32 C/D frag
typedef __attribute__((ext_vector_type(4)))  unsigned u32x4;

#define Nx 2048
#define CTXx 2049
#define KCAP 2112          // 33 tiles of 64; pad keys stay poison (finite bf16) & masked
#define QSCALE 0.18033688f // 0.125 * log2(e): softmax computed as 2^(S*log2e) = e^S

__device__ __forceinline__ short f2bs(float x){   // float -> bf16 bits (RNE)
    unsigned u = __builtin_bit_cast(unsigned, x);
    u = (u + 0x7fffu + ((u >> 16) & 1u)) >> 16;
    return (short)u;
}
// truncating pack: (hi16 of b)<<16 | (hi16 of a) — 1 v_perm_b32
__device__ __forceinline__ unsigned pack_trunc(float a, float b){
    return __builtin_amdgcn_perm(__builtin_bit_cast(unsigned, b),
                                 __builtin_bit_cast(unsigned, a), 0x07060302u);
}

// ---------------- fused LN1 (blocks 0..2047) + weight prep (2048..2192) ----------------
__global__ void __launch_bounds__(256) ln1_prep_kernel(const float* __restrict__ x,
                                                       const float* __restrict__ g,
                                                       short* __restrict__ xnb,
                                                       const float* __restrict__ Wq,
                                                       const float* __restrict__ Wkv,
                                                       const float* __restrict__ Wout,
                                                       const float* __restrict__ nkv,
                                                       short* __restrict__ WcatT,
                                                       short* __restrict__ WoutT,
                                                       short* __restrict__ kb,
                                                       short* __restrict__ vbt){
    __shared__ float ls[64][65];
    int t = threadIdx.x;
    if (blockIdx.x < 2048){    // ---- LN1: wave per row, fp32 -> bf16 ----
        int w = t >> 6, lane = t & 63;
        size_t row = (size_t)blockIdx.x * 4 + w;
        const float* xr = x + row * 512 + lane * 8;
        float4 a = *(const float4*)xr;
        float4 b = *(const float4*)(xr + 4);
        float s = a.x + a.y + a.z + a.w + b.x + b.y + b.z + b.w;
        float q = a.x*a.x + a.y*a.y + a.z*a.z + a.w*a.w
                + b.x*b.x + b.y*b.y + b.z*b.z + b.w*b.w;
        #pragma unroll
        for (int m = 1; m < 64; m <<= 1){ s += __shfl_xor(s, m, 64); q += __shfl_xor(q, m, 64); }
        float mu  = s * (1.f / 512.f);
        float var = fmaxf(q * (1.f / 512.f) - mu * mu, 0.f);
        float r   = rsqrtf(var + 1e-5f);
        const float* gr = g + lane * 8;
        float4 g0 = *(const float4*)gr;
        float4 g1 = *(const float4*)(gr + 4);
        bf16x8 o;
        o[0] = f2bs((a.x - mu) * r * g0.x); o[1] = f2bs((a.y - mu) * r * g0.y);
        o[2] = f2bs((a.z - mu) * r * g0.z); o[3] = f2bs((a.w - mu) * r * g0.w);
        o[4] = f2bs((b.x - mu) * r * g1.x); o[5] = f2bs((b.y - mu) * r * g1.y);
        o[6] = f2bs((b.z - mu) * r * g1.z); o[7] = f2bs((b.w - mu) * r * g1.w);
        *(bf16x8*)(xnb + row * 512 + lane * 8) = o;
        return;
    }
    int bid = blockIdx.x - 2048;
    if (bid == 144){   // null K/V row (key 0, all batches)
        int b = t >> 6, d = t & 63;
        kb[((size_t)b * KCAP) * 64 + d] = f2bs(nkv[d]);
        vbt[((size_t)b * 64 + d) * KCAP + 0] = f2bs(nkv[64 + d]);
        return;
    }
    // ---- LDS-tiled transpose: 0..79 WcatT (640x512), 80..143 WoutT (512x512) ----
    bool isOut = (bid >= 80);
    int b2 = isOut ? bid - 80 : bid;
    int ntile = isOut ? (b2 & 7) : (b2 % 10);
    int ktile = isOut ? (b2 >> 3) : (b2 / 10);
    int n0 = ntile * 64, k0 = ktile * 64;
    #pragma unroll
    for (int rr = 0; rr < 64; rr += 16){   // coalesced float4 reads of W[k][n]
        int r = rr + (t >> 4), c = (t & 15) * 4;
        float4 v;
        if (isOut)            v = *(const float4*)(Wout + (size_t)(k0 + r) * 512 + n0 + c);
        else if (n0 < 512)    v = *(const float4*)(Wq   + (size_t)(k0 + r) * 512 + n0 + c);
        else                  v = *(const float4*)(Wkv  + (size_t)(k0 + r) * 128 + (n0 - 512) + c);
        ls[c + 0][r] = v.x; ls[c + 1][r] = v.y; ls[c + 2][r] = v.z; ls[c + 3][r] = v.w;
    }
    __syncthreads();
    int rn = t >> 2, kc = (t & 3) * 16;    // coalesced 32B bf16 writes of W^T[n][k]
    short tmp[16];
    #pragma unroll
    for (int j = 0; j < 16; j++) tmp[j] = f2bs(ls[rn][kc + j]);
    short* dst = (isOut ? WoutT : WcatT) + (size_t)(n0 + rn) * 512 + k0 + kc;
    *(int4*)dst       = *(int4*)&tmp[0];
    *(int4*)(dst + 8) = *(int4*)&tmp[8];
}

// ---------------- GEMM QKV: LDS-free. 256 blocks x 32 rows x 640 cols; wave = 160 cols ----------------
// A and B frags are 16B-contiguous in global (B pre-transposed) -> direct global->reg loads,
// zero barriers; reuse via L1/L2 (B = 0.65 MB, L2-resident). Reg ping-pong over k-steps of 32.
__global__ void __launch_bounds__(256, 1) gemm_qkv(const short* __restrict__ A,
                                                   const short* __restrict__ BwT,
                                                   short* __restrict__ qb,
                                                   short* __restrict__ kb,
                                                   short* __restrict__ vbt){
    int t = threadIdx.x, lane = t & 63, w = t >> 6;
    int l16 = lane & 15, quad = lane >> 4;
    int row0 = blockIdx.x * 32;
    const short* aB = A   + (size_t)(row0 + l16) * 512 + quad * 8;
    const short* bB = BwT + (size_t)(w * 160 + l16) * 512 + quad * 8;
    f32x4 acc[2][10];
    #pragma unroll
    for (int mt = 0; mt < 2; mt++)
        #pragma unroll
        for (int nt = 0; nt < 10; nt++) acc[mt][nt] = (f32x4){0.f, 0.f, 0.f, 0.f};
    bf16x8 af[2][2], bf[2][10];
    #pragma unroll
    for (int mt = 0; mt < 2; mt++) af[0][mt] = *(const bf16x8*)(aB + mt * 8192);
    #pragma unroll
    for (int nt = 0; nt < 10; nt++) bf[0][nt] = *(const bf16x8*)(bB + nt * 8192);
    #pragma unroll
    for (int it = 0; it < 16; ++it){
        int cur = it & 1, nxt = cur ^ 1;
        if (it < 15){
            int kn = (it + 1) * 32;
            #pragma unroll
            for (int mt = 0; mt < 2; mt++) af[nxt][mt] = *(const bf16x8*)(aB + mt * 8192 + kn);
            #pragma unroll
            for (int nt = 0; nt < 10; nt++) bf[nxt][nt] = *(const bf16x8*)(bB + nt * 8192 + kn);
        }
        #pragma unroll
        for (int mt = 0; mt < 2; mt++)
            #pragma unroll
            for (int nt = 0; nt < 10; nt++)
                acc[mt][nt] = __builtin_amdgcn_mfma_f32_16x16x32_bf16(af[cur][mt], bf[cur][nt], acc[mt][nt], 0, 0, 0);
    }
    #pragma unroll
    for (int mt = 0; mt < 2; mt++)
        #pragma unroll
        for (int nt = 0; nt < 10; nt++)
            #pragma unroll
            for (int r = 0; r < 4; r++){
                int row = row0 + mt * 16 + quad * 4 + r;
                int col = w * 160 + nt * 16 + l16;
                float v = acc[mt][nt][r];
                int bb = row >> 11, ii = row & 2047;
                if (col < 512){
                    qb[(size_t)row * 512 + col] = f2bs(v * QSCALE);
                } else if (col < 576){
                    kb[((size_t)bb * KCAP + ii + 1) * 64 + (col - 512)] = f2bs(v);
                } else {
                    vbt[((size_t)bb * 64 + (col - 576)) * KCAP + ii + 1] = f2bs(v);
                }
            }
}

// ---------------- GEMM OUT + LN2 fused: 256 blocks x 32 rows x 512 cols; wave = 128 cols ----------------
// LDS-free GEMM (direct frag loads), then LN over the full row: per-lane partials -> l16
// butterfly -> 4-wave LDS reduce -> normalize in regs -> fp32 out. Kills the zb round-trip.
__global__ void __launch_bounds__(256, 1) gemm_out_ln2(const short* __restrict__ A,
                                                       const short* __restrict__ BwT,
                                                       const float* __restrict__ og,
                                                       float* __restrict__ out){
    __shared__ float Sred[4][32], Qred[4][32];
    int t = threadIdx.x, lane = t & 63, w = t >> 6;
    int l16 = lane & 15, quad = lane >> 4;
    int row0 = blockIdx.x * 32;
    const short* aB = A   + (size_t)(row0 + l16) * 512 + quad * 8;
    const short* bB = BwT + (size_t)(w * 128 + l16) * 512 + quad * 8;
    f32x4 acc[2][8];
    #pragma unroll
    for (int mt = 0; mt < 2; mt++)
        #pragma unroll
        for (int nt = 0; nt < 8; nt++) acc[mt][nt] = (f32x4){0.f, 0.f, 0.f, 0.f};
    bf16x8 af[2][2], bf[2][8];
    #pragma unroll
    for (int mt = 0; mt < 2; mt++) af[0][mt] = *(const bf16x8*)(aB + mt * 8192);
    #pragma unroll
    for (int nt = 0; nt < 8; nt++) bf[0][nt] = *(const bf16x8*)(bB + nt * 8192);
    #pragma unroll
    for (int it = 0; it < 16; ++it){
        int cur = it & 1, nxt = cur ^ 1;
        if (it < 15){
            int kn = (it + 1) * 32;
            #pragma unroll
            for (int mt = 0; mt < 2; mt++) af[nxt][mt] = *(const bf16x8*)(aB + mt * 8192 + kn);
            #pragma unroll
            for (int nt = 0; nt < 8; nt++) bf[nxt][nt] = *(const bf16x8*)(bB + nt * 8192 + kn);
        }
        #pragma unroll
        for (int mt = 0; mt < 2; mt++)
            #pragma unroll
            for (int nt = 0; nt < 8; nt++)
                acc[mt][nt] = __builtin_amdgcn_mfma_f32_16x16x32_bf16(af[cur][mt], bf[cur][nt], acc[mt][nt], 0, 0, 0);
    }
    // ---- LN over full rows: lane partials (8 nt) -> butterfly over l16 -> LDS over 4 waves ----
    #pragma unroll
    for (int mt = 0; mt < 2; mt++)
        #pragma unroll
        for (int r = 0; r < 4; r++){
            float s = 0.f, q = 0.f;
            #pragma unroll
            for (int nt = 0; nt < 8; nt++){
                float v = acc[mt][nt][r];
                s += v; q += v * v;
            }
            #pragma unroll
            for (int m = 1; m < 16; m <<= 1){ s += __shfl_xor(s, m, 64); q += __shfl_xor(q, m, 64); }
            if (l16 == 0){
                int rl = mt * 16 + quad * 4 + r;
                Sred[w][rl] = s; Qred[w][rl] = q;
            }
        }
    __syncthreads();
    #pragma unroll
    for (int mt = 0; mt < 2; mt++)
        #pragma unroll
        for (int r = 0; r < 4; r++){
            int rl = mt * 16 + quad * 4 + r;
            float S = Sred[0][rl] + Sred[1][rl] + Sred[2][rl] + Sred[3][rl];
            float Q = Qred[0][rl] + Qred[1][rl] + Qred[2][rl] + Qred[3][rl];
            float mu  = S * (1.f / 512.f);
            float var = fmaxf(Q * (1.f / 512.f) - mu * mu, 0.f);
            float rstd = rsqrtf(var + 1e-5f);
            float* op = out + (size_t)(row0 + rl) * 512;
            #pragma unroll
            for (int nt = 0; nt < 8; nt++){
                int col = w * 128 + nt * 16 + l16;
                op[col] = (acc[mt][nt][r] - mu) * rstd * og[col];
            }
        }
}

// ---------------- MFMA attention v5 (unchanged from R8): K+V LDS dbuf, 1 barrier/tile ----------------
__global__ void __launch_bounds__(256, 2) attn_kernel(const short* __restrict__ qb,
                                                      const short* __restrict__ kb,
                                                      const short* __restrict__ vbt,
                                                      const int* __restrict__ mask,
                                                      short* __restrict__ ob){
    __shared__ short Ks[2][64][72];   // [buf][key][d]
    __shared__ short Vt[2][64][72];   // [buf][d][key], key cols bit2<->bit3 swapped
    int t = threadIdx.x;
    int lane = t & 63, w = t >> 6;
    int n32 = lane & 31, hb = lane >> 5;
    int b = blockIdx.y, i0 = blockIdx.x * 16;
    int head = 2 * w + (n32 >> 4), row = i0 + (n32 & 15);
    bf16x8 qf[4];
    {
        const short* qp = qb + ((size_t)(b * Nx + row)) * 512 + head * 64 + hb * 8;
        #pragma unroll
        for (int ks = 0; ks < 4; ks++) qf[ks] = *(const bf16x8*)(qp + ks * 16);
    }
    bf16x8 ones;
    #pragma unroll
    for (int j = 0; j < 8; j++) ones[j] = (short)0x3F80;   // bf16 1.0
    f32x16 oacc[2], lacc;
    #pragma unroll
    for (int j = 0; j < 16; j++){ oacc[0][j] = 0.f; oacc[1][j] = 0.f; lacc[j] = 0.f; }

    int skey = t >> 2, sd = (t & 3) * 16;   // K staging: 64 keys x 64 d
    int vd   = t >> 2, vk = (t & 3) * 16;   // V staging: 64 d x 64 keys
    const short* kgp = kb  + (size_t)b * KCAP * 64 + skey * 64 + sd;
    const short* vgp = vbt + ((size_t)b * 64 + vd) * KCAP + vk;
    const int* mrow = mask + b * Nx;

    int4 pk0 = *(const int4*)(kgp);
    int4 pk1 = *(const int4*)(kgp + 8);
    int4 pv0 = *(const int4*)(vgp);
    int4 pv1 = *(const int4*)(vgp + 8);
    int mok = (lane == 0) ? 1 : ((lane < CTXx) ? mrow[lane - 1] : 0);

    int p = 0;
    for (int jt = 0; jt < 33; ++jt){
        *(int4*)&Ks[p][skey][sd]     = pk0;
        *(int4*)&Ks[p][skey][sd + 8] = pk1;
        *(int4*)&Vt[p][vd][vk]       = make_int4(pv0.x, pv0.y, pv1.x, pv1.y);
        *(int4*)&Vt[p][vd][vk + 8]   = make_int4(pv0.z, pv0.w, pv1.z, pv1.w);
        unsigned long long bal = __ballot(mok != 0);
        __syncthreads();
        int jn = (jt + 1) * 64;
        if (jt + 1 < 33){
            pk0 = *(const int4*)(kgp + (size_t)jn * 64);
            pk1 = *(const int4*)(kgp + (size_t)jn * 64 + 8);
            pv0 = *(const int4*)(vgp + jn);
            pv1 = *(const int4*)(vgp + jn + 8);
            int jg = jn + lane;
            mok = (jg < CTXx) ? mrow[jg - 1] : 0;
        }
        f32x16 sf[2];
        #pragma unroll
        for (int i = 0; i < 2; i++)
            #pragma unroll
            for (int j = 0; j < 16; j++) sf[i][j] = 0.f;
        #pragma unroll
        for (int ks = 0; ks < 4; ks++){
            #pragma unroll
            for (int kt = 0; kt < 2; kt++){
                bf16x8 kf = *(const bf16x8*)&Ks[p][kt * 32 + n32][ks * 16 + hb * 8];
                sf[kt] = __builtin_amdgcn_mfma_f32_32x32x16_bf16(kf, qf[ks], sf[kt], 0, 0, 0);
            }
        }
        unsigned mlo = (unsigned)(bal >> (4 * hb));
        unsigned mhi = (unsigned)(bal >> (32 + 4 * hb));
        unsigned pg[8][2];
        #pragma unroll
        for (int kt = 0; kt < 2; kt++){
            unsigned mm = kt ? mhi : mlo;
            #pragma unroll
            for (int g4 = 0; g4 < 4; g4++){
                float pr[4];
                #pragma unroll
                for (int tt = 0; tt < 4; tt++){
                    float e = __builtin_amdgcn_exp2f(sf[kt][g4 * 4 + tt]);
                    pr[tt] = ((mm >> (8 * g4 + tt)) & 1u) ? e : 0.f;
                }
                pg[kt * 4 + g4][0] = pack_trunc(pr[0], pr[1]);
                pg[kt * 4 + g4][1] = pack_trunc(pr[2], pr[3]);
            }
        }
        #pragma unroll
        for (int s = 0; s < 4; s++){
            bf16x8 pa = __builtin_bit_cast(bf16x8,
                (u32x4){pg[2 * s][0], pg[2 * s][1], pg[2 * s + 1][0], pg[2 * s + 1][1]});
            lacc = __builtin_amdgcn_mfma_f32_32x32x16_bf16(pa, ones, lacc, 0, 0, 0);
            #pragma unroll
            for (int nt = 0; nt < 2; nt++){
                bf16x8 vf = *(const bf16x8*)&Vt[p][nt * 32 + n32][s * 16 + hb * 8];
                oacc[nt] = __builtin_amdgcn_mfma_f32_32x32x16_bf16(pa, vf, oacc[nt], 0, 0, 0);
            }
        }
        p ^= 1;
    }
    #pragma unroll
    for (int r = 0; r < 16; r++){
        float linv = 1.f / lacc[r];
        int hr = (r & 3) + 8 * (r >> 2) + 4 * hb;
        int grow = i0 + (hr & 15);
        int ghead = 2 * w + (hr >> 4);
        short* op = ob + ((size_t)(b * Nx + grow)) * 512 + ghead * 64 + n32;
        op[0]  = f2bs(oacc[0][r] * linv);
        op[32] = f2bs(oacc[1][r] * linv);
    }
}

extern "C" void kernel_launch(void* const* d_in, const int* in_sizes, int n_in,
                              void* d_out, int out_size, void* d_ws, size_t ws_size,
                              hipStream_t stream){
    const float* x     = (const float*)d_in[0];
    const int*   mask  = (const int*)  d_in[1];
    const float* gamma = (const float*)d_in[2];
    const float* Wq    = (const float*)d_in[3];
    const float* Wkv   = (const float*)d_in[4];
    const float* nkv   = (const float*)d_in[5];
    const float* Wout  = (const float*)d_in[6];
    const float* og    = (const float*)d_in[7];
    float* out = (float*)d_out;

    short* xnb   = (short*)d_ws;                 // 4194304
    short* qb    = xnb + (size_t)4194304;        // 4194304
    short* kb    = qb  + (size_t)4194304;        // 4*KCAP*64 = 540672
    short* vbt   = kb  + (size_t)540672;         // 540672
    short* WcatT = vbt + (size_t)540672;         // 327680
    short* WoutT = WcatT + (size_t)327680;       // 262144
    short* ob    = xnb;                          // alias: xnb dead after gemm_qkv

    ln1_prep_kernel<<<2193, 256, 0, stream>>>(x, gamma, xnb, Wq, Wkv, Wout, nkv,
                                              WcatT, WoutT, kb, vbt);
    gemm_qkv    <<<256, 256, 0, stream>>>(xnb, WcatT, qb, kb, vbt);
    attn_kernel <<<dim3(128, 4), 256, 0, stream>>>(qb, kb, vbt, mask, ob);
    gemm_out_ln2<<<256, 256, 0, stream>>>(ob, WoutT, og, out);
}